// Round 6
// baseline (704.392 us; speedup 1.0000x reference)
//
#include <hip/hip_runtime.h>
#include <hip/hip_cooperative_groups.h>

namespace cg = cooperative_groups;

typedef __bf16 bf16x8 __attribute__((ext_vector_type(8)));
typedef float f32x4 __attribute__((ext_vector_type(4)));

namespace {
constexpr int kCX = 352, kCY = 400;
constexpr int kCL = 2 * kCY * kCX;   // 281600 voxels (CZ==1)
constexpr float kVX = 0.2f, kVY = 0.2f;
constexpr float kXOFF = 0.1f;    // VX/2 + X0
constexpr float kYOFF = -39.9f;  // VY/2 + Y0
constexpr float kZOFF = -1.0f;   // VZ/2 + Z0 (cz==0 always)
constexpr int P = 64;            // sorted points per fused block
constexpr int NPmax = 84;        // capacity incl. voxel-straddle extension
constexpr int NBLK = kCL / 256;  // 1100 prep blocks (1 thread : 1 voxel)
}

__device__ __forceinline__ float bf2f(unsigned short u) {
  return __uint_as_float(((unsigned int)u) << 16);
}
__device__ __forceinline__ unsigned short f2bf(float f) {
  unsigned int u = __float_as_uint(f);
  u += 0x7fffu + ((u >> 16) & 1u);  // RNE
  return (unsigned short)(u >> 16);
}
__device__ __forceinline__ void split_bf(float v, unsigned short& h,
                                         unsigned short& l) {
  h = f2bf(v);
  l = f2bf(v - bf2f(h));
}

union BF8 { unsigned short u[8]; bf16x8 v; };

__device__ __forceinline__ int voxel_of(int4 c) {
  return ((c.x + c.y) * kCY + c.z) * kCX + c.w;  // CZ==1
}

// ---------------- k_prep: memset+hist+scan+zero-fill+scatter, 1 launch -----
__global__ __launch_bounds__(256, 8) void k_prep(
    const int4* __restrict__ coors, unsigned int* __restrict__ cnt,
    unsigned int* __restrict__ vid, unsigned int* __restrict__ bsum,
    unsigned int* __restrict__ cursor, uint2* __restrict__ pv,
    float4* __restrict__ out4, int n) {
  cg::grid_group grid = cg::this_grid();
  __shared__ unsigned int tmp[256];
  int t = threadIdx.x;
  int b = blockIdx.x;
  int tid = b * 256 + t;  // 0..kCL-1, exactly one thread per voxel

  // ph0: zero counts (d_ws is poisoned before every launch)
  cnt[tid] = 0u;
  grid.sync();

  // ph1: histogram + vid cache
  for (int p = tid; p < n; p += kCL) {
    int v = voxel_of(coors[p]);
    vid[p] = (unsigned int)v;
    atomicAdd(&cnt[v], 1u);
  }
  grid.sync();

  // ph2: block-local exclusive scan of cnt + per-block sum
  unsigned int myc = cnt[tid];
  tmp[t] = myc;
  __syncthreads();
  for (int off = 1; off < 256; off <<= 1) {
    unsigned int x = (t >= off) ? tmp[t - off] : 0u;
    __syncthreads();
    tmp[t] += x;
    __syncthreads();
  }
  cursor[tid] = tmp[t] - myc;  // local exclusive prefix
  if (t == 255) bsum[b] = tmp[255];
  grid.sync();

  // ph3: each block redundantly prefixes bsum[0..b-1]; fix cursor;
  //      zero-fill empty voxel output rows (cnt is final).
  {
    unsigned int s = 0;
    for (int i = t; i < b; i += 256) s += bsum[i];
    __syncthreads();  // tmp reuse
    tmp[t] = s;
    __syncthreads();
    for (int off = 128; off > 0; off >>= 1) {
      if (t < off) tmp[t] += tmp[t + off];
      __syncthreads();
    }
    cursor[tid] += tmp[0];
  }
  if (myc == 0u) {
    float4 z = float4{0.f, 0.f, 0.f, 0.f};
    float4* o = out4 + (size_t)tid * 16;
#pragma unroll
    for (int i = 0; i < 16; ++i) o[i] = z;
  }
  grid.sync();

  // ph4: counting-sort scatter of {point, vid} records
  for (int p = tid; p < n; p += kCL) {
    unsigned int v = vid[p];
    unsigned int pos = atomicAdd(&cursor[v], 1u);
    pv[pos] = uint2{(unsigned int)p, v};
  }
}

// ---------------- fused VFE ----------------
__global__ __launch_bounds__(256, 4) void k_fused(
    const float4* __restrict__ feat,
    const uint2* __restrict__ pv,
    const float* __restrict__ W1,
    const float* __restrict__ scale1, const float* __restrict__ shift1,
    const float* __restrict__ W2,
    const float* __restrict__ scale2, const float* __restrict__ shift2,
    float* __restrict__ out, int n) {
  __shared__ unsigned int gvid[128];   // vid window [i0n-1, i0n+126]
  __shared__ union {
    float Fraw[128][4];                // raw features (phases A..D)
    float Cst[4][16][20];              // per-wave GEMM2 C staging (loop)
  } u;
  __shared__ float F[NPmax][12];       // 11-dim features, row-major (f4 reads)
  __shared__ unsigned short Ph[NPmax][72];  // pf1, bf16
  __shared__ unsigned short Vh[NPmax][72];  // per-slot vmax(pf1), bf16
  __shared__ int slot_of[NPmax];
  __shared__ int slot_start[NPmax + 1];
  __shared__ unsigned int slot_vox[NPmax];
  __shared__ int sA[NPmax + 2];        // voxel-aligned group boundaries
  __shared__ unsigned long long bmask[2];
  __shared__ int sNG;

  int t = threadIdx.x;
  int lane = t & 63, wv = t >> 6;
  long long i0n = (long long)blockIdx.x * P;

  // A: window load (sorted-order gather)
  if (t < 128) {
    long long pos = i0n - 1 + t;
    unsigned int v = 0xFFFFFFFFu;
    float4 f = float4{0.f, 0.f, 0.f, 0.f};
    if (pos >= 0 && pos < n) {
      uint2 e = pv[pos];
      v = e.y;
      f = feat[e.x];
    }
    gvid[t] = v;
    u.Fraw[t][0] = f.x; u.Fraw[t][1] = f.y;
    u.Fraw[t][2] = f.z; u.Fraw[t][3] = f.w;
  }
  __syncthreads();

  // B: every wave redundantly computes the voxel-complete range; waves 0,1
  //    ballot slot (voxel-run) boundaries.
  int s_off, np;
  {
    bool eq = (blockIdx.x > 0) && (gvid[1 + lane] == gvid[0]);
    unsigned long long m = __ballot(eq);
    s_off = (~m == 0ull) ? 64 : (__ffsll((long long)~m) - 1);
    unsigned int lastv = gvid[P];
    bool eq2 = (1 + P + lane < 128) && (lastv != 0xFFFFFFFFu) &&
               (gvid[1 + P + lane] == lastv);
    unsigned long long m2 = __ballot(eq2);
    int e_off = __ffsll((long long)~m2) - 1;  // lane63 false -> well-defined
    long long ecap = (long long)(P + e_off);
    if (ecap > n - i0n) ecap = n - i0n;
    np = (int)ecap - s_off;
    if (np > NPmax) np = NPmax;
    bool valid = (t < np);
    bool bf = valid && (t == 0 || gvid[1 + s_off + t] != gvid[s_off + t]);
    unsigned long long bm = __ballot(bf);
    if (lane == 0 && wv < 2) bmask[wv] = bm;
  }
  __syncthreads();
  if (np <= 0) return;

  // C: slot structure
  unsigned long long m0 = bmask[0], m1 = bmask[1];
  int ns = __popcll(m0) + __popcll(m1);
  if (t < np) {
    int j = t;
    int slot = (j < 64) ? (__popcll(m0 << (63 - j)) - 1)
                        : (__popcll(m0) + __popcll(m1 << (63 - (j - 64))) - 1);
    slot_of[j] = slot;
    bool bf = (j == 0) || (gvid[1 + s_off + j] != gvid[s_off + j]);
    if (bf) { slot_start[slot] = j; slot_vox[slot] = gvid[1 + s_off + j]; }
  }
  if (t == 0) slot_start[ns] = np;
  __syncthreads();

  // D: per-point features (own-slot mean recomputed per point) + group chain
  if (t < np) {
    int s = slot_of[t];
    int r0 = slot_start[s], r1 = slot_start[s + 1];
    float sx = 0.f, sy = 0.f, sz = 0.f;
    for (int j = r0; j < r1; ++j) {
      sx += u.Fraw[1 + s_off + j][0];
      sy += u.Fraw[1 + s_off + j][1];
      sz += u.Fraw[1 + s_off + j][2];
    }
    float rc = 1.0f / (float)(r1 - r0);
    int jw = 1 + s_off + t;
    float fx = u.Fraw[jw][0], fy = u.Fraw[jw][1];
    float fz = u.Fraw[jw][2], fr = u.Fraw[jw][3];
    unsigned int v = gvid[jw];
    unsigned int cx = v % (unsigned int)kCX;
    unsigned int cy = (v / (unsigned int)kCX) % (unsigned int)kCY;
    float4 q0 = float4{fx, fy, fz, fr};
    float4 q1 = float4{fx - sx * rc, fy - sy * rc, fz - sz * rc,
                       fx - ((float)cx * kVX + kXOFF)};
    float4 q2 = float4{fy - ((float)cy * kVY + kYOFF), fz - kZOFF,
                       sqrtf(fx * fx + fy * fy + fz * fz), 0.0f};
    *(float4*)&F[t][0] = q0;
    *(float4*)&F[t][4] = q1;
    *(float4*)&F[t][8] = q2;
  }
  if (t == 255) {
    int g = 0, cur = 0;
    sA[0] = 0;
    while (cur < np) {
      int nxt;
      if (cur + 16 >= np) nxt = np;
      else {
        nxt = slot_start[slot_of[cur + 16]];
        if (nxt <= cur) nxt = cur + 16;  // >16-pt voxel guard
      }
      ++g; sA[g] = nxt; cur = nxt;
    }
    sNG = g;
  }
  __syncthreads();

  // E: GEMM1 on VALU, exact f32 (K=11); row-major F -> 3x ds_read_b128
  //    broadcast per point (j is wave-uniform).
  {
    int col = t & 63;
    float w[11];
#pragma unroll
    for (int k = 0; k < 11; ++k) w[k] = W1[k * 64 + col];
    float s1 = scale1[col], sh1 = shift1[col];
    for (int j = wv; j < np; j += 4) {
      float4 f0 = *(const float4*)&F[j][0];
      float4 f1 = *(const float4*)&F[j][4];
      float4 f2 = *(const float4*)&F[j][8];
      float acc = f0.x * w[0] + f0.y * w[1] + f0.z * w[2] + f0.w * w[3] +
                  f1.x * w[4] + f1.y * w[5] + f1.z * w[6] + f1.w * w[7] +
                  f2.x * w[8] + f2.y * w[9] + f2.z * w[10];
      Ph[j][col] = f2bf(fmaxf(acc * s1 + sh1, 0.0f));
    }
  }
  __syncthreads();

  // F: per-slot vmax of pf1 (bf16>=0: u16 compare == value compare)
  {
    int col = t & 63;
    for (int s = wv; s < ns; s += 4) {
      int r0 = slot_start[s], r1 = slot_start[s + 1];
      unsigned short mx = 0;
      for (int j = r0; j < r1; ++j) {
        unsigned short x = Ph[j][col];
        if (x > mx) mx = x;
      }
      Vh[s][col] = mx;
    }
  }
  __syncthreads();

  // G: GEMM2 (MFMA, bf16 A x split-W2) — barrier-free group loop.
  int m = lane & 15, q = lane >> 4;
  int col = wv * 16 + m;
  BF8 b2h[4], b2l[4];
#pragma unroll
  for (int kb = 0; kb < 4; ++kb)
#pragma unroll
    for (int i = 0; i < 8; ++i)
      split_bf(W2[(kb * 32 + q * 8 + i) * 64 + col], b2h[kb].u[i],
               b2l[kb].u[i]);
  float s2 = scale2[col], sh2 = shift2[col];
  int ng = sNG;
  for (int g = 0; g < ng; ++g) {
    int base = sA[g], lim = sA[g + 1];
    int jj = base + m;
    if (jj > np - 1) jj = np - 1;  // pad rows (ignored in reduce)
    int sl = slot_of[jj];
    f32x4 c2 = {0.f, 0.f, 0.f, 0.f};
#pragma unroll
    for (int kb = 0; kb < 4; ++kb) {
      const unsigned short* ph = (kb < 2) ? &Ph[jj][kb * 32 + q * 8]
                                          : &Vh[sl][(kb - 2) * 32 + q * 8];
      BF8 a;
      *(ushort4*)&a.u[0] = *(const ushort4*)ph;
      *(ushort4*)&a.u[4] = *(const ushort4*)(ph + 4);
      c2 = __builtin_amdgcn_mfma_f32_16x16x32_bf16(a.v, b2h[kb].v, c2, 0, 0, 0);
      c2 = __builtin_amdgcn_mfma_f32_16x16x32_bf16(a.v, b2l[kb].v, c2, 0, 0, 0);
    }
    // per-wave private transpose (same-wave LDS RAW is in-order: no barrier)
#pragma unroll
    for (int r = 0; r < 4; ++r)
      u.Cst[wv][q * 4 + r][m] = fmaxf(c2[r] * s2 + sh2, 0.0f);
    int s_lo = slot_of[base], s_hi = slot_of[lim - 1];
    for (int s = s_lo + q; s <= s_hi; s += 4) {
      int r0 = slot_start[s], r1 = slot_start[s + 1];
      if (r1 > lim) r1 = lim;
      float mx = 0.f;
      for (int j = r0; j < r1; ++j)
        mx = fmaxf(mx, u.Cst[wv][j - base][m]);
      out[(size_t)slot_vox[s] * 64 + col] = mx;
    }
  }
}

extern "C" void kernel_launch(void* const* d_in, const int* in_sizes, int n_in,
                              void* d_out, int out_size, void* d_ws, size_t ws_size,
                              hipStream_t stream) {
  const float4* feat = (const float4*)d_in[0];
  const int4* coors = (const int4*)d_in[1];
  const float* W1 = (const float*)d_in[2];
  const float* scale1 = (const float*)d_in[3];
  const float* shift1 = (const float*)d_in[4];
  const float* W2 = (const float*)d_in[5];
  const float* scale2 = (const float*)d_in[6];
  const float* shift2 = (const float*)d_in[7];
  int n = in_sizes[0] / 4;  // 500000 points

  // Workspace (~10.5 MB): cnt | cursor | bsum | vid[n] | pv[n] (uint2)
  unsigned int* cnt = (unsigned int*)d_ws;
  unsigned int* cursor = cnt + kCL;
  unsigned int* bsum = cursor + kCL;
  unsigned int* vid = bsum + 1104;
  uint2* pv = (uint2*)(vid + ((n + 1) & ~1));
  float4* out4 = (float4*)d_out;

  void* args[] = {(void*)&coors, (void*)&cnt, (void*)&vid, (void*)&bsum,
                  (void*)&cursor, (void*)&pv, (void*)&out4, (void*)&n};
  hipLaunchCooperativeKernel((const void*)k_prep, dim3(NBLK), dim3(256),
                             args, 0, stream);
  k_fused<<<(n + P - 1) / P, 256, 0, stream>>>(
      feat, pv, W1, scale1, shift1, W2, scale2, shift2, (float*)d_out, n);
}

// Round 7
// 615.087 us; speedup vs baseline: 1.1452x; 1.1452x over previous
//
#include <hip/hip_runtime.h>

typedef __bf16 bf16x8 __attribute__((ext_vector_type(8)));
typedef float f32x4 __attribute__((ext_vector_type(4)));

namespace {
constexpr int kCX = 352, kCY = 400;
constexpr int kCL = 2 * kCY * kCX;   // 281600 voxels (CZ==1)
constexpr float kVX = 0.2f, kVY = 0.2f;
constexpr float kXOFF = 0.1f;    // VX/2 + X0
constexpr float kYOFF = -39.9f;  // VY/2 + Y0
constexpr float kZOFF = -1.0f;   // VZ/2 + Z0 (cz==0 always)
constexpr int P = 64;            // sorted points per fused block
constexpr int NPmax = 84;        // capacity incl. voxel-straddle extension
constexpr int NBLK = kCL / 256;  // 1100 scan blocks (1 thread : 1 voxel)
}

__device__ __forceinline__ float bf2f(unsigned short u) {
  return __uint_as_float(((unsigned int)u) << 16);
}
__device__ __forceinline__ unsigned short f2bf(float f) {
  unsigned int u = __float_as_uint(f);
  u += 0x7fffu + ((u >> 16) & 1u);  // RNE
  return (unsigned short)(u >> 16);
}
__device__ __forceinline__ void split_bf(float v, unsigned short& h,
                                         unsigned short& l) {
  h = f2bf(v);
  l = f2bf(v - bf2f(h));
}

union BF8 { unsigned short u[8]; bf16x8 v; };

__device__ __forceinline__ int voxel_of(int4 c) {
  return ((c.x + c.y) * kCY + c.z) * kCX + c.w;  // CZ==1
}

// ---------------- histogram + vid cache ----------------
__global__ void k_hist(const int4* __restrict__ coors,
                       unsigned int* __restrict__ cnt,
                       unsigned int* __restrict__ vid, int n) {
  int p = blockIdx.x * blockDim.x + threadIdx.x;
  if (p >= n) return;
  int v = voxel_of(coors[p]);
  vid[p] = (unsigned int)v;
  atomicAdd(&cnt[v], 1u);
}

// ------- scan (decoupled lookback, one dispatch) + empty-voxel zero-fill ----
// state[b] = (flag<<32)|value; flag: 0=invalid, 1=aggregate, 2=inclusive.
// All 1100 blocks are co-resident (4 waves, 1 KB LDS) -> spin is safe.
__global__ __launch_bounds__(256) void k_scanzero(
    const unsigned int* __restrict__ cnt,
    unsigned long long* __restrict__ state,
    unsigned int* __restrict__ cursor,
    float4* __restrict__ out4) {
  __shared__ unsigned int tmp[256];
  __shared__ unsigned int sPrefix;
  int t = threadIdx.x, b = blockIdx.x;
  int tid = b * 256 + t;
  unsigned int myc = cnt[tid];
  tmp[t] = myc;
  __syncthreads();
  for (int off = 1; off < 256; off <<= 1) {  // inclusive block scan
    unsigned int x = (t >= off) ? tmp[t - off] : 0u;
    __syncthreads();
    tmp[t] += x;
    __syncthreads();
  }
  if (t == 0) {
    unsigned int agg = tmp[255];
    if (b == 0) {
      __hip_atomic_store(&state[0], (2ull << 32) | agg, __ATOMIC_RELEASE,
                         __HIP_MEMORY_SCOPE_AGENT);
      sPrefix = 0u;
    } else {
      __hip_atomic_store(&state[b], (1ull << 32) | agg, __ATOMIC_RELEASE,
                         __HIP_MEMORY_SCOPE_AGENT);
      unsigned int pre = 0u;
      int j = b - 1;
      for (;;) {
        unsigned long long s = __hip_atomic_load(
            &state[j], __ATOMIC_ACQUIRE, __HIP_MEMORY_SCOPE_AGENT);
        unsigned int fl = (unsigned int)(s >> 32);
        if (fl == 0u) { __builtin_amdgcn_s_sleep(1); continue; }
        pre += (unsigned int)s;
        if (fl == 2u) break;
        --j;
      }
      __hip_atomic_store(&state[b], (2ull << 32) | (pre + agg),
                         __ATOMIC_RELEASE, __HIP_MEMORY_SCOPE_AGENT);
      sPrefix = pre;
    }
  }
  __syncthreads();
  cursor[tid] = sPrefix + tmp[t] - myc;  // global exclusive prefix
  if (myc == 0u) {                       // zero-fill empty voxel rows
    float4 z = float4{0.f, 0.f, 0.f, 0.f};
    float4* o = out4 + (size_t)tid * 16;
#pragma unroll
    for (int i = 0; i < 16; ++i) o[i] = z;
  }
}

// ---------------- scatter: counting-sort, fused {point,vid} record ---------
__global__ void k_scatter(const unsigned int* __restrict__ vid,
                          unsigned int* __restrict__ cursor,
                          uint2* __restrict__ pv, int n) {
  int p = blockIdx.x * blockDim.x + threadIdx.x;
  if (p >= n) return;
  unsigned int v = vid[p];
  unsigned int pos = atomicAdd(&cursor[v], 1u);
  pv[pos] = uint2{(unsigned int)p, v};
}

// ---------------- fused VFE ----------------
__global__ __launch_bounds__(256, 4) void k_fused(
    const float4* __restrict__ feat,
    const uint2* __restrict__ pv,
    const float* __restrict__ W1,
    const float* __restrict__ scale1, const float* __restrict__ shift1,
    const float* __restrict__ W2,
    const float* __restrict__ scale2, const float* __restrict__ shift2,
    float* __restrict__ out, int n) {
  __shared__ unsigned int gvid[128];   // vid window [i0n-1, i0n+126]
  __shared__ union {
    float Fraw[128][4];                // raw features (phases A..D)
    float Cst[4][16][20];              // per-wave GEMM2 C staging (loop)
  } u;
  __shared__ float F[NPmax][12];       // 11-dim features, row-major (f4 reads)
  __shared__ unsigned short Ph[NPmax][72];  // pf1, bf16
  __shared__ unsigned short Vh[NPmax][72];  // per-slot vmax(pf1), bf16
  __shared__ int slot_of[NPmax];
  __shared__ int slot_start[NPmax + 1];
  __shared__ unsigned int slot_vox[NPmax];
  __shared__ int sA[NPmax + 2];        // voxel-aligned group boundaries
  __shared__ unsigned long long bmask[2];
  __shared__ int sNG;

  int t = threadIdx.x;
  int lane = t & 63, wv = t >> 6;
  long long i0n = (long long)blockIdx.x * P;

  // A: window load (sorted-order gather)
  if (t < 128) {
    long long pos = i0n - 1 + t;
    unsigned int v = 0xFFFFFFFFu;
    float4 f = float4{0.f, 0.f, 0.f, 0.f};
    if (pos >= 0 && pos < n) {
      uint2 e = pv[pos];
      v = e.y;
      f = feat[e.x];
    }
    gvid[t] = v;
    u.Fraw[t][0] = f.x; u.Fraw[t][1] = f.y;
    u.Fraw[t][2] = f.z; u.Fraw[t][3] = f.w;
  }
  __syncthreads();

  // B: every wave redundantly computes the voxel-complete range; waves 0,1
  //    ballot slot (voxel-run) boundaries.
  int s_off, np;
  {
    bool eq = (blockIdx.x > 0) && (gvid[1 + lane] == gvid[0]);
    unsigned long long m = __ballot(eq);
    s_off = (~m == 0ull) ? 64 : (__ffsll((long long)~m) - 1);
    unsigned int lastv = gvid[P];
    bool eq2 = (1 + P + lane < 128) && (lastv != 0xFFFFFFFFu) &&
               (gvid[1 + P + lane] == lastv);
    unsigned long long m2 = __ballot(eq2);
    int e_off = __ffsll((long long)~m2) - 1;  // lane63 false -> well-defined
    long long ecap = (long long)(P + e_off);
    if (ecap > n - i0n) ecap = n - i0n;
    np = (int)ecap - s_off;
    if (np > NPmax) np = NPmax;
    bool valid = (t < np);
    bool bf = valid && (t == 0 || gvid[1 + s_off + t] != gvid[s_off + t]);
    unsigned long long bm = __ballot(bf);
    if (lane == 0 && wv < 2) bmask[wv] = bm;
  }
  __syncthreads();
  if (np <= 0) return;

  // C: slot structure
  unsigned long long m0 = bmask[0], m1 = bmask[1];
  int ns = __popcll(m0) + __popcll(m1);
  if (t < np) {
    int j = t;
    int slot = (j < 64) ? (__popcll(m0 << (63 - j)) - 1)
                        : (__popcll(m0) + __popcll(m1 << (63 - (j - 64))) - 1);
    slot_of[j] = slot;
    bool bf = (j == 0) || (gvid[1 + s_off + j] != gvid[s_off + j]);
    if (bf) { slot_start[slot] = j; slot_vox[slot] = gvid[1 + s_off + j]; }
  }
  if (t == 0) slot_start[ns] = np;
  __syncthreads();

  // D: per-point features (own-slot mean recomputed per point) + group chain
  if (t < np) {
    int s = slot_of[t];
    int r0 = slot_start[s], r1 = slot_start[s + 1];
    float sx = 0.f, sy = 0.f, sz = 0.f;
    for (int j = r0; j < r1; ++j) {
      sx += u.Fraw[1 + s_off + j][0];
      sy += u.Fraw[1 + s_off + j][1];
      sz += u.Fraw[1 + s_off + j][2];
    }
    float rc = 1.0f / (float)(r1 - r0);
    int jw = 1 + s_off + t;
    float fx = u.Fraw[jw][0], fy = u.Fraw[jw][1];
    float fz = u.Fraw[jw][2], fr = u.Fraw[jw][3];
    unsigned int v = gvid[jw];
    unsigned int cx = v % (unsigned int)kCX;
    unsigned int cy = (v / (unsigned int)kCX) % (unsigned int)kCY;
    float4 q0 = float4{fx, fy, fz, fr};
    float4 q1 = float4{fx - sx * rc, fy - sy * rc, fz - sz * rc,
                       fx - ((float)cx * kVX + kXOFF)};
    float4 q2 = float4{fy - ((float)cy * kVY + kYOFF), fz - kZOFF,
                       sqrtf(fx * fx + fy * fy + fz * fz), 0.0f};
    *(float4*)&F[t][0] = q0;
    *(float4*)&F[t][4] = q1;
    *(float4*)&F[t][8] = q2;
  }
  if (t == 255) {
    int g = 0, cur = 0;
    sA[0] = 0;
    while (cur < np) {
      int nxt;
      if (cur + 16 >= np) nxt = np;
      else {
        nxt = slot_start[slot_of[cur + 16]];
        if (nxt <= cur) nxt = cur + 16;  // >16-pt voxel guard
      }
      ++g; sA[g] = nxt; cur = nxt;
    }
    sNG = g;
  }
  __syncthreads();

  // E: GEMM1 on VALU, exact f32 (K=11); row-major F -> 3x ds_read_b128
  //    broadcast per point (j is wave-uniform).
  {
    int col = t & 63;
    float w[11];
#pragma unroll
    for (int k = 0; k < 11; ++k) w[k] = W1[k * 64 + col];
    float s1 = scale1[col], sh1 = shift1[col];
    for (int j = wv; j < np; j += 4) {
      float4 f0 = *(const float4*)&F[j][0];
      float4 f1 = *(const float4*)&F[j][4];
      float4 f2 = *(const float4*)&F[j][8];
      float acc = f0.x * w[0] + f0.y * w[1] + f0.z * w[2] + f0.w * w[3] +
                  f1.x * w[4] + f1.y * w[5] + f1.z * w[6] + f1.w * w[7] +
                  f2.x * w[8] + f2.y * w[9] + f2.z * w[10];
      Ph[j][col] = f2bf(fmaxf(acc * s1 + sh1, 0.0f));
    }
  }
  __syncthreads();

  // F: per-slot vmax of pf1 (bf16>=0: u16 compare == value compare)
  {
    int col = t & 63;
    for (int s = wv; s < ns; s += 4) {
      int r0 = slot_start[s], r1 = slot_start[s + 1];
      unsigned short mx = 0;
      for (int j = r0; j < r1; ++j) {
        unsigned short x = Ph[j][col];
        if (x > mx) mx = x;
      }
      Vh[s][col] = mx;
    }
  }
  __syncthreads();

  // G: GEMM2 (MFMA, bf16 A x split-W2) — barrier-free group loop.
  int m = lane & 15, q = lane >> 4;
  int col = wv * 16 + m;
  BF8 b2h[4], b2l[4];
#pragma unroll
  for (int kb = 0; kb < 4; ++kb)
#pragma unroll
    for (int i = 0; i < 8; ++i)
      split_bf(W2[(kb * 32 + q * 8 + i) * 64 + col], b2h[kb].u[i],
               b2l[kb].u[i]);
  float s2 = scale2[col], sh2 = shift2[col];
  int ng = sNG;
  for (int g = 0; g < ng; ++g) {
    int base = sA[g], lim = sA[g + 1];
    int jj = base + m;
    if (jj > np - 1) jj = np - 1;  // pad rows (ignored in reduce)
    int sl = slot_of[jj];
    f32x4 c2 = {0.f, 0.f, 0.f, 0.f};
#pragma unroll
    for (int kb = 0; kb < 4; ++kb) {
      const unsigned short* ph = (kb < 2) ? &Ph[jj][kb * 32 + q * 8]
                                          : &Vh[sl][(kb - 2) * 32 + q * 8];
      BF8 a;
      *(ushort4*)&a.u[0] = *(const ushort4*)ph;
      *(ushort4*)&a.u[4] = *(const ushort4*)(ph + 4);
      c2 = __builtin_amdgcn_mfma_f32_16x16x32_bf16(a.v, b2h[kb].v, c2, 0, 0, 0);
      c2 = __builtin_amdgcn_mfma_f32_16x16x32_bf16(a.v, b2l[kb].v, c2, 0, 0, 0);
    }
    // per-wave private transpose (same-wave LDS RAW is in-order: no barrier)
#pragma unroll
    for (int r = 0; r < 4; ++r)
      u.Cst[wv][q * 4 + r][m] = fmaxf(c2[r] * s2 + sh2, 0.0f);
    int s_lo = slot_of[base], s_hi = slot_of[lim - 1];
    for (int s = s_lo + q; s <= s_hi; s += 4) {
      int r0 = slot_start[s], r1 = slot_start[s + 1];
      if (r1 > lim) r1 = lim;
      float mx = 0.f;
      for (int j = r0; j < r1; ++j)
        mx = fmaxf(mx, u.Cst[wv][j - base][m]);
      out[(size_t)slot_vox[s] * 64 + col] = mx;
    }
  }
}

extern "C" void kernel_launch(void* const* d_in, const int* in_sizes, int n_in,
                              void* d_out, int out_size, void* d_ws, size_t ws_size,
                              hipStream_t stream) {
  const float4* feat = (const float4*)d_in[0];
  const int4* coors = (const int4*)d_in[1];
  const float* W1 = (const float*)d_in[2];
  const float* scale1 = (const float*)d_in[3];
  const float* shift1 = (const float*)d_in[4];
  const float* W2 = (const float*)d_in[5];
  const float* scale2 = (const float*)d_in[6];
  const float* shift2 = (const float*)d_in[7];
  int n = in_sizes[0] / 4;  // 500000 points

  // Workspace (~10.5 MB): cnt[kCL] | state[1104 u64] | cursor[kCL] |
  //                       vid[n] | pv[n] (uint2)
  unsigned int* cnt = (unsigned int*)d_ws;
  unsigned long long* state = (unsigned long long*)(cnt + kCL);
  unsigned int* cursor = (unsigned int*)(state + 1104);
  unsigned int* vid = cursor + kCL;
  uint2* pv = (uint2*)(vid + ((n + 1) & ~1));

  // zero cnt + lookback state in one memset
  hipMemsetAsync(cnt, 0, (size_t)kCL * 4 + 1104 * 8, stream);

  k_hist<<<(n + 255) / 256, 256, 0, stream>>>(coors, cnt, vid, n);
  k_scanzero<<<NBLK, 256, 0, stream>>>(cnt, state, cursor, (float4*)d_out);
  k_scatter<<<(n + 255) / 256, 256, 0, stream>>>(vid, cursor, pv, n);
  k_fused<<<(n + P - 1) / P, 256, 0, stream>>>(
      feat, pv, W1, scale1, shift1, W2, scale2, shift2, (float*)d_out, n);
}

// Round 8
// 329.513 us; speedup vs baseline: 2.1377x; 1.8667x over previous
//
#include <hip/hip_runtime.h>

typedef __bf16 bf16x8 __attribute__((ext_vector_type(8)));
typedef float f32x4 __attribute__((ext_vector_type(4)));

namespace {
constexpr int kCX = 352, kCY = 400;
constexpr int kCL = 2 * kCY * kCX;   // 281600 voxels (CZ==1)
constexpr float kVX = 0.2f, kVY = 0.2f;
constexpr float kXOFF = 0.1f;    // VX/2 + X0
constexpr float kYOFF = -39.9f;  // VY/2 + Y0
constexpr float kZOFF = -1.0f;   // VZ/2 + Z0 (cz==0 always)
constexpr int P = 64;            // sorted points per fused block
constexpr int NPmax = 84;        // capacity incl. voxel-straddle extension
constexpr int NBLK = kCL / 256;  // 1100 scan blocks (1 thread : 1 voxel)
}

__device__ __forceinline__ float bf2f(unsigned short u) {
  return __uint_as_float(((unsigned int)u) << 16);
}
__device__ __forceinline__ unsigned short f2bf(float f) {
  unsigned int u = __float_as_uint(f);
  u += 0x7fffu + ((u >> 16) & 1u);  // RNE
  return (unsigned short)(u >> 16);
}
__device__ __forceinline__ void split_bf(float v, unsigned short& h,
                                         unsigned short& l) {
  h = f2bf(v);
  l = f2bf(v - bf2f(h));
}
__device__ __forceinline__ unsigned int wave_sum(unsigned int v) {
#pragma unroll
  for (int off = 1; off < 64; off <<= 1) v += __shfl_xor(v, off);
  return v;
}

union BF8 { unsigned short u[8]; bf16x8 v; };

__device__ __forceinline__ int voxel_of(int4 c) {
  return ((c.x + c.y) * kCY + c.z) * kCX + c.w;  // CZ==1
}

// ---------------- histogram + vid cache ----------------
__global__ void k_hist(const int4* __restrict__ coors,
                       unsigned int* __restrict__ cnt,
                       unsigned int* __restrict__ vid, int n) {
  int p = blockIdx.x * blockDim.x + threadIdx.x;
  if (p >= n) return;
  int v = voxel_of(coors[p]);
  vid[p] = (unsigned int)v;
  atomicAdd(&cnt[v], 1u);
}

// ------- scan (decoupled lookback, WAVE-PARALLEL window) + zero-fill -------
// state[b] = (flag<<32)|value; flag: 0=invalid, 1=aggregate, 2=inclusive.
// Lane i inspects state[b-1-i]; j<0 acts as virtual inclusive 0. Blocks never
// wait on predecessors' inclusives (aggregates suffice to reach j<0), so the
// worst case is ceil(1100/64)=18 windows — no serial chain.
__global__ __launch_bounds__(256) void k_scanzero(
    const unsigned int* __restrict__ cnt,
    unsigned long long* __restrict__ state,
    unsigned int* __restrict__ cursor,
    float4* __restrict__ out4) {
  __shared__ unsigned int tmp[256];
  __shared__ unsigned int sPrefix;
  int t = threadIdx.x, b = blockIdx.x;
  int tid = b * 256 + t;
  unsigned int myc = cnt[tid];
  tmp[t] = myc;
  __syncthreads();
  for (int off = 1; off < 256; off <<= 1) {  // inclusive block scan
    unsigned int x = (t >= off) ? tmp[t - off] : 0u;
    __syncthreads();
    tmp[t] += x;
    __syncthreads();
  }
  if (t < 64) {  // wave 0 does publication + lookback
    unsigned int agg = tmp[255];
    if (t == 0)
      __hip_atomic_store(&state[b], ((b == 0 ? 2ull : 1ull) << 32) | agg,
                         __ATOMIC_RELEASE, __HIP_MEMORY_SCOPE_AGENT);
    if (b == 0) {
      if (t == 0) sPrefix = 0u;
    } else {
      unsigned int pre = 0u;
      int base = b - 1;
      for (;;) {
        int j = base - t;
        unsigned long long s =
            (j >= 0) ? __hip_atomic_load(&state[j], __ATOMIC_ACQUIRE,
                                         __HIP_MEMORY_SCOPE_AGENT)
                     : (2ull << 32);
        unsigned int fl = (unsigned int)(s >> 32);
        unsigned long long inc = __ballot(fl == 2u);
        unsigned long long val = __ballot(fl >= 1u);
        int istar = inc ? (__ffsll((long long)inc) - 1) : 64;
        unsigned long long need =
            (istar >= 64) ? ~0ull
                          : ((istar == 0) ? 0ull : ((1ull << istar) - 1ull));
        if ((val & need) != need) {
          __builtin_amdgcn_s_sleep(1);
          continue;
        }
        if (istar < 64) {
          pre += wave_sum((t <= istar) ? (unsigned int)s : 0u);
          break;
        }
        pre += wave_sum((unsigned int)s);
        base -= 64;
      }
      if (t == 0) {
        __hip_atomic_store(&state[b], (2ull << 32) | (pre + agg),
                           __ATOMIC_RELEASE, __HIP_MEMORY_SCOPE_AGENT);
        sPrefix = pre;
      }
    }
  }
  __syncthreads();
  cursor[tid] = sPrefix + tmp[t] - myc;  // global exclusive prefix
  if (myc == 0u) {                       // zero-fill empty voxel rows
    float4 z = float4{0.f, 0.f, 0.f, 0.f};
    float4* o = out4 + (size_t)tid * 16;
#pragma unroll
    for (int i = 0; i < 16; ++i) o[i] = z;
  }
}

// ---------------- scatter: counting-sort, fused {point,vid} record ---------
__global__ void k_scatter(const unsigned int* __restrict__ vid,
                          unsigned int* __restrict__ cursor,
                          uint2* __restrict__ pv, int n) {
  int p = blockIdx.x * blockDim.x + threadIdx.x;
  if (p >= n) return;
  unsigned int v = vid[p];
  unsigned int pos = atomicAdd(&cursor[v], 1u);
  pv[pos] = uint2{(unsigned int)p, v};
}

// ---------------- fused VFE ----------------
__global__ __launch_bounds__(256, 4) void k_fused(
    const float4* __restrict__ feat,
    const uint2* __restrict__ pv,
    const float* __restrict__ W1,
    const float* __restrict__ scale1, const float* __restrict__ shift1,
    const float* __restrict__ W2,
    const float* __restrict__ scale2, const float* __restrict__ shift2,
    float* __restrict__ out, int n) {
  __shared__ unsigned int gvid[128];   // vid window [i0n-1, i0n+126]
  __shared__ union {
    float Fraw[128][4];                // raw features (phases A..D)
    float Cst[4][16][20];              // per-wave GEMM2 C staging (loop)
  } u;
  __shared__ float F[NPmax][12];       // 11-dim features, row-major (f4 reads)
  __shared__ unsigned short Ph[NPmax][72];  // pf1, bf16
  __shared__ unsigned short Vh[NPmax][72];  // per-slot vmax(pf1), bf16
  __shared__ int slot_of[NPmax];
  __shared__ int slot_start[NPmax + 1];
  __shared__ unsigned int slot_vox[NPmax];
  __shared__ int sA[NPmax + 2];        // voxel-aligned group boundaries
  __shared__ unsigned long long bmask[2];
  __shared__ int sNG;

  int t = threadIdx.x;
  int lane = t & 63, wv = t >> 6;
  long long i0n = (long long)blockIdx.x * P;

  // A: window load (sorted-order gather)
  if (t < 128) {
    long long pos = i0n - 1 + t;
    unsigned int v = 0xFFFFFFFFu;
    float4 f = float4{0.f, 0.f, 0.f, 0.f};
    if (pos >= 0 && pos < n) {
      uint2 e = pv[pos];
      v = e.y;
      f = feat[e.x];
    }
    gvid[t] = v;
    u.Fraw[t][0] = f.x; u.Fraw[t][1] = f.y;
    u.Fraw[t][2] = f.z; u.Fraw[t][3] = f.w;
  }
  __syncthreads();

  // B: every wave redundantly computes the voxel-complete range; waves 0,1
  //    ballot slot (voxel-run) boundaries.
  int s_off, np;
  {
    bool eq = (blockIdx.x > 0) && (gvid[1 + lane] == gvid[0]);
    unsigned long long m = __ballot(eq);
    s_off = (~m == 0ull) ? 64 : (__ffsll((long long)~m) - 1);
    unsigned int lastv = gvid[P];
    bool eq2 = (1 + P + lane < 128) && (lastv != 0xFFFFFFFFu) &&
               (gvid[1 + P + lane] == lastv);
    unsigned long long m2 = __ballot(eq2);
    int e_off = __ffsll((long long)~m2) - 1;  // lane63 false -> well-defined
    long long ecap = (long long)(P + e_off);
    if (ecap > n - i0n) ecap = n - i0n;
    np = (int)ecap - s_off;
    if (np > NPmax) np = NPmax;
    bool valid = (t < np);
    bool bf = valid && (t == 0 || gvid[1 + s_off + t] != gvid[s_off + t]);
    unsigned long long bm = __ballot(bf);
    if (lane == 0 && wv < 2) bmask[wv] = bm;
  }
  __syncthreads();
  if (np <= 0) return;

  // C: slot structure
  unsigned long long m0 = bmask[0], m1 = bmask[1];
  int ns = __popcll(m0) + __popcll(m1);
  if (t < np) {
    int j = t;
    int slot = (j < 64) ? (__popcll(m0 << (63 - j)) - 1)
                        : (__popcll(m0) + __popcll(m1 << (63 - (j - 64))) - 1);
    slot_of[j] = slot;
    bool bf = (j == 0) || (gvid[1 + s_off + j] != gvid[s_off + j]);
    if (bf) { slot_start[slot] = j; slot_vox[slot] = gvid[1 + s_off + j]; }
  }
  if (t == 0) slot_start[ns] = np;
  __syncthreads();

  // D: per-point features (own-slot mean recomputed per point) + group chain
  if (t < np) {
    int s = slot_of[t];
    int r0 = slot_start[s], r1 = slot_start[s + 1];
    float sx = 0.f, sy = 0.f, sz = 0.f;
    for (int j = r0; j < r1; ++j) {
      sx += u.Fraw[1 + s_off + j][0];
      sy += u.Fraw[1 + s_off + j][1];
      sz += u.Fraw[1 + s_off + j][2];
    }
    float rc = 1.0f / (float)(r1 - r0);
    int jw = 1 + s_off + t;
    float fx = u.Fraw[jw][0], fy = u.Fraw[jw][1];
    float fz = u.Fraw[jw][2], fr = u.Fraw[jw][3];
    unsigned int v = gvid[jw];
    unsigned int cx = v % (unsigned int)kCX;
    unsigned int cy = (v / (unsigned int)kCX) % (unsigned int)kCY;
    float4 q0 = float4{fx, fy, fz, fr};
    float4 q1 = float4{fx - sx * rc, fy - sy * rc, fz - sz * rc,
                       fx - ((float)cx * kVX + kXOFF)};
    float4 q2 = float4{fy - ((float)cy * kVY + kYOFF), fz - kZOFF,
                       sqrtf(fx * fx + fy * fy + fz * fz), 0.0f};
    *(float4*)&F[t][0] = q0;
    *(float4*)&F[t][4] = q1;
    *(float4*)&F[t][8] = q2;
  }
  if (t == 255) {
    int g = 0, cur = 0;
    sA[0] = 0;
    while (cur < np) {
      int nxt;
      if (cur + 16 >= np) nxt = np;
      else {
        nxt = slot_start[slot_of[cur + 16]];
        if (nxt <= cur) nxt = cur + 16;  // >16-pt voxel guard
      }
      ++g; sA[g] = nxt; cur = nxt;
    }
    sNG = g;
  }
  __syncthreads();

  // E: GEMM1 on VALU, exact f32 (K=11); row-major F -> 3x ds_read_b128
  //    broadcast per point (j is wave-uniform).
  {
    int col = t & 63;
    float w[11];
#pragma unroll
    for (int k = 0; k < 11; ++k) w[k] = W1[k * 64 + col];
    float s1 = scale1[col], sh1 = shift1[col];
    for (int j = wv; j < np; j += 4) {
      float4 f0 = *(const float4*)&F[j][0];
      float4 f1 = *(const float4*)&F[j][4];
      float4 f2 = *(const float4*)&F[j][8];
      float acc = f0.x * w[0] + f0.y * w[1] + f0.z * w[2] + f0.w * w[3] +
                  f1.x * w[4] + f1.y * w[5] + f1.z * w[6] + f1.w * w[7] +
                  f2.x * w[8] + f2.y * w[9] + f2.z * w[10];
      Ph[j][col] = f2bf(fmaxf(acc * s1 + sh1, 0.0f));
    }
  }
  __syncthreads();

  // F: per-slot vmax of pf1 (bf16>=0: u16 compare == value compare)
  {
    int col = t & 63;
    for (int s = wv; s < ns; s += 4) {
      int r0 = slot_start[s], r1 = slot_start[s + 1];
      unsigned short mx = 0;
      for (int j = r0; j < r1; ++j) {
        unsigned short x = Ph[j][col];
        if (x > mx) mx = x;
      }
      Vh[s][col] = mx;
    }
  }
  __syncthreads();

  // G: GEMM2 (MFMA, bf16 A x split-W2) — barrier-free group loop.
  int m = lane & 15, q = lane >> 4;
  int col = wv * 16 + m;
  BF8 b2h[4], b2l[4];
#pragma unroll
  for (int kb = 0; kb < 4; ++kb)
#pragma unroll
    for (int i = 0; i < 8; ++i)
      split_bf(W2[(kb * 32 + q * 8 + i) * 64 + col], b2h[kb].u[i],
               b2l[kb].u[i]);
  float s2 = scale2[col], sh2 = shift2[col];
  int ng = sNG;
  for (int g = 0; g < ng; ++g) {
    int base = sA[g], lim = sA[g + 1];
    int jj = base + m;
    if (jj > np - 1) jj = np - 1;  // pad rows (ignored in reduce)
    int sl = slot_of[jj];
    f32x4 c2 = {0.f, 0.f, 0.f, 0.f};
#pragma unroll
    for (int kb = 0; kb < 4; ++kb) {
      const unsigned short* ph = (kb < 2) ? &Ph[jj][kb * 32 + q * 8]
                                          : &Vh[sl][(kb - 2) * 32 + q * 8];
      BF8 a;
      *(ushort4*)&a.u[0] = *(const ushort4*)ph;
      *(ushort4*)&a.u[4] = *(const ushort4*)(ph + 4);
      c2 = __builtin_amdgcn_mfma_f32_16x16x32_bf16(a.v, b2h[kb].v, c2, 0, 0, 0);
      c2 = __builtin_amdgcn_mfma_f32_16x16x32_bf16(a.v, b2l[kb].v, c2, 0, 0, 0);
    }
    // per-wave private transpose (same-wave LDS RAW is in-order: no barrier)
#pragma unroll
    for (int r = 0; r < 4; ++r)
      u.Cst[wv][q * 4 + r][m] = fmaxf(c2[r] * s2 + sh2, 0.0f);
    int s_lo = slot_of[base], s_hi = slot_of[lim - 1];
    for (int s = s_lo + q; s <= s_hi; s += 4) {
      int r0 = slot_start[s], r1 = slot_start[s + 1];
      if (r1 > lim) r1 = lim;
      float mx = 0.f;
      for (int j = r0; j < r1; ++j)
        mx = fmaxf(mx, u.Cst[wv][j - base][m]);
      out[(size_t)slot_vox[s] * 64 + col] = mx;
    }
  }
}

extern "C" void kernel_launch(void* const* d_in, const int* in_sizes, int n_in,
                              void* d_out, int out_size, void* d_ws, size_t ws_size,
                              hipStream_t stream) {
  const float4* feat = (const float4*)d_in[0];
  const int4* coors = (const int4*)d_in[1];
  const float* W1 = (const float*)d_in[2];
  const float* scale1 = (const float*)d_in[3];
  const float* shift1 = (const float*)d_in[4];
  const float* W2 = (const float*)d_in[5];
  const float* scale2 = (const float*)d_in[6];
  const float* shift2 = (const float*)d_in[7];
  int n = in_sizes[0] / 4;  // 500000 points

  // Workspace (~10.5 MB): cnt[kCL] | state[1104 u64] | cursor[kCL] |
  //                       vid[n] | pv[n] (uint2)
  unsigned int* cnt = (unsigned int*)d_ws;
  unsigned long long* state = (unsigned long long*)(cnt + kCL);
  unsigned int* cursor = (unsigned int*)(state + 1104);
  unsigned int* vid = cursor + kCL;
  uint2* pv = (uint2*)(vid + ((n + 1) & ~1));

  // zero cnt + lookback state in one memset
  hipMemsetAsync(cnt, 0, (size_t)kCL * 4 + 1104 * 8, stream);

  k_hist<<<(n + 255) / 256, 256, 0, stream>>>(coors, cnt, vid, n);
  k_scanzero<<<NBLK, 256, 0, stream>>>(cnt, state, cursor, (float4*)d_out);
  k_scatter<<<(n + 255) / 256, 256, 0, stream>>>(vid, cursor, pv, n);
  k_fused<<<(n + P - 1) / P, 256, 0, stream>>>(
      feat, pv, W1, scale1, shift1, W2, scale2, shift2, (float*)d_out, n);
}

// Round 9
// 242.107 us; speedup vs baseline: 2.9094x; 1.3610x over previous
//
#include <hip/hip_runtime.h>

typedef __bf16 bf16x8 __attribute__((ext_vector_type(8)));
typedef float f32x4 __attribute__((ext_vector_type(4)));

namespace {
constexpr int kCX = 352, kCY = 400;
constexpr int kCL = 2 * kCY * kCX;   // 281600 voxels (CZ==1), < 2^19
constexpr float kVX = 0.2f, kVY = 0.2f;
constexpr float kXOFF = 0.1f;    // VX/2 + X0
constexpr float kYOFF = -39.9f;  // VY/2 + Y0
constexpr float kZOFF = -1.0f;   // VZ/2 + Z0 (cz==0 always)
constexpr int P = 64;            // sorted points per fused block
constexpr int NPmax = 84;        // capacity incl. voxel-straddle extension
constexpr int NBLK = kCL / 256;  // 1100 alloc blocks (1 thread : 1 voxel)
}

__device__ __forceinline__ float bf2f(unsigned short u) {
  return __uint_as_float(((unsigned int)u) << 16);
}
__device__ __forceinline__ unsigned short f2bf(float f) {
  unsigned int u = __float_as_uint(f);
  u += 0x7fffu + ((u >> 16) & 1u);  // RNE
  return (unsigned short)(u >> 16);
}
__device__ __forceinline__ void split_bf(float v, unsigned short& h,
                                         unsigned short& l) {
  h = f2bf(v);
  l = f2bf(v - bf2f(h));
}

union BF8 { unsigned short u[8]; bf16x8 v; };

__device__ __forceinline__ int voxel_of(int4 c) {
  return ((c.x + c.y) * kCY + c.z) * kCX + c.w;  // CZ==1
}

// ---------------- hist: counts + {vid | rank<<19} cache ----------------
// atomicAdd's return value IS the point's rank within its voxel.
__global__ void k_hist(const int4* __restrict__ coors,
                       unsigned int* __restrict__ cnt,
                       unsigned int* __restrict__ vid, int n) {
  int p = blockIdx.x * blockDim.x + threadIdx.x;
  if (p >= n) return;
  int v = voxel_of(coors[p]);
  unsigned int r = atomicAdd(&cnt[v], 1u);
  vid[p] = (unsigned int)v | (r << 19);
}

// ------- alloc: block-local scan + ONE relaxed atomicAdd per block --------
// Voxel runs need only be contiguous, not globally ordered -> no prefix scan,
// no device-scope acquire/release (which flush per-XCD L2 on gfx950 -- the
// R7/R6 lesson). Also zero-fills empty voxel output rows.
__global__ __launch_bounds__(256) void k_alloczero(
    const unsigned int* __restrict__ cnt,
    unsigned int* __restrict__ total,
    unsigned int* __restrict__ cursor,
    float4* __restrict__ out4) {
  __shared__ unsigned int tmp[256];
  __shared__ unsigned int sBase;
  int t = threadIdx.x, b = blockIdx.x;
  int tid = b * 256 + t;
  unsigned int myc = cnt[tid];
  tmp[t] = myc;
  __syncthreads();
  for (int off = 1; off < 256; off <<= 1) {  // inclusive block scan
    unsigned int x = (t >= off) ? tmp[t - off] : 0u;
    __syncthreads();
    tmp[t] += x;
    __syncthreads();
  }
  if (t == 255) sBase = atomicAdd(total, tmp[255]);
  __syncthreads();
  cursor[tid] = sBase + tmp[t] - myc;  // base of this voxel's run
  if (myc == 0u) {                     // zero-fill empty voxel rows
    float4 z = float4{0.f, 0.f, 0.f, 0.f};
    float4* o = out4 + (size_t)tid * 16;
#pragma unroll
    for (int i = 0; i < 16; ++i) o[i] = z;
  }
}

// ---------------- scatter: atomic-free (cursor base + cached rank) ---------
__global__ void k_scatter(const unsigned int* __restrict__ vid,
                          const unsigned int* __restrict__ cursor,
                          uint2* __restrict__ pv, int n) {
  int p = blockIdx.x * blockDim.x + threadIdx.x;
  if (p >= n) return;
  unsigned int vr = vid[p];
  unsigned int v = vr & 0x7FFFFu;
  unsigned int pos = cursor[v] + (vr >> 19);
  pv[pos] = uint2{(unsigned int)p, v};
}

// ---------------- fused VFE ----------------
__global__ __launch_bounds__(256, 5) void k_fused(
    const float4* __restrict__ feat,
    const uint2* __restrict__ pv,
    const float* __restrict__ W1,
    const float* __restrict__ scale1, const float* __restrict__ shift1,
    const float* __restrict__ W2,
    const float* __restrict__ scale2, const float* __restrict__ shift2,
    float* __restrict__ out, int n) {
  __shared__ unsigned int gvid[128];   // vid window [i0n-1, i0n+126]
  __shared__ union {
    float Fraw[128][4];                // raw features (phases A..D)
    float Cst[4][16][17];              // per-wave GEMM2 C staging (phase G)
  } uA;
  __shared__ union {
    float F[NPmax][12];                // 11-dim features (D..E)
    unsigned short Vh[NPmax][72];      // per-slot vmax(pf1), bf16 (F..G)
  } uB;
  __shared__ unsigned short Ph[NPmax][72];  // pf1, bf16
  __shared__ int slot_of[NPmax];
  __shared__ int slot_start[NPmax + 1];
  __shared__ unsigned int slot_vox[NPmax];
  __shared__ int sA[NPmax + 2];        // voxel-aligned group boundaries
  __shared__ unsigned long long bmask[2];
  __shared__ int sNG;

  int t = threadIdx.x;
  int lane = t & 63, wv = t >> 6;
  long long i0n = (long long)blockIdx.x * P;

  // A: window load (sorted-order gather)
  if (t < 128) {
    long long pos = i0n - 1 + t;
    unsigned int v = 0xFFFFFFFFu;
    float4 f = float4{0.f, 0.f, 0.f, 0.f};
    if (pos >= 0 && pos < n) {
      uint2 e = pv[pos];
      v = e.y;
      f = feat[e.x];
    }
    gvid[t] = v;
    uA.Fraw[t][0] = f.x; uA.Fraw[t][1] = f.y;
    uA.Fraw[t][2] = f.z; uA.Fraw[t][3] = f.w;
  }
  __syncthreads();

  // B: every wave redundantly computes the voxel-complete range; waves 0,1
  //    ballot slot (voxel-run) boundaries.
  int s_off, np;
  {
    bool eq = (blockIdx.x > 0) && (gvid[1 + lane] == gvid[0]);
    unsigned long long m = __ballot(eq);
    s_off = (~m == 0ull) ? 64 : (__ffsll((long long)~m) - 1);
    unsigned int lastv = gvid[P];
    bool eq2 = (1 + P + lane < 128) && (lastv != 0xFFFFFFFFu) &&
               (gvid[1 + P + lane] == lastv);
    unsigned long long m2 = __ballot(eq2);
    int e_off = __ffsll((long long)~m2) - 1;  // lane63 false -> well-defined
    long long ecap = (long long)(P + e_off);
    if (ecap > n - i0n) ecap = n - i0n;
    np = (int)ecap - s_off;
    if (np > NPmax) np = NPmax;
    bool valid = (t < np);
    bool bf = valid && (t == 0 || gvid[1 + s_off + t] != gvid[s_off + t]);
    unsigned long long bm = __ballot(bf);
    if (lane == 0 && wv < 2) bmask[wv] = bm;
  }
  __syncthreads();
  if (np <= 0) return;

  // C: slot structure
  unsigned long long m0 = bmask[0], m1 = bmask[1];
  int ns = __popcll(m0) + __popcll(m1);
  if (t < np) {
    int j = t;
    int slot = (j < 64) ? (__popcll(m0 << (63 - j)) - 1)
                        : (__popcll(m0) + __popcll(m1 << (63 - (j - 64))) - 1);
    slot_of[j] = slot;
    bool bf = (j == 0) || (gvid[1 + s_off + j] != gvid[s_off + j]);
    if (bf) { slot_start[slot] = j; slot_vox[slot] = gvid[1 + s_off + j]; }
  }
  if (t == 0) slot_start[ns] = np;
  __syncthreads();

  // D: per-point features (own-slot mean recomputed per point) + group chain
  if (t < np) {
    int s = slot_of[t];
    int r0 = slot_start[s], r1 = slot_start[s + 1];
    float sx = 0.f, sy = 0.f, sz = 0.f;
    for (int j = r0; j < r1; ++j) {
      sx += uA.Fraw[1 + s_off + j][0];
      sy += uA.Fraw[1 + s_off + j][1];
      sz += uA.Fraw[1 + s_off + j][2];
    }
    float rc = 1.0f / (float)(r1 - r0);
    int jw = 1 + s_off + t;
    float fx = uA.Fraw[jw][0], fy = uA.Fraw[jw][1];
    float fz = uA.Fraw[jw][2], fr = uA.Fraw[jw][3];
    unsigned int v = gvid[jw];
    unsigned int cx = v % (unsigned int)kCX;
    unsigned int cy = (v / (unsigned int)kCX) % (unsigned int)kCY;
    float4 q0 = float4{fx, fy, fz, fr};
    float4 q1 = float4{fx - sx * rc, fy - sy * rc, fz - sz * rc,
                       fx - ((float)cx * kVX + kXOFF)};
    float4 q2 = float4{fy - ((float)cy * kVY + kYOFF), fz - kZOFF,
                       sqrtf(fx * fx + fy * fy + fz * fz), 0.0f};
    *(float4*)&uB.F[t][0] = q0;
    *(float4*)&uB.F[t][4] = q1;
    *(float4*)&uB.F[t][8] = q2;
  }
  if (t == 255) {
    int g = 0, cur = 0;
    sA[0] = 0;
    while (cur < np) {
      int nxt;
      if (cur + 16 >= np) nxt = np;
      else {
        nxt = slot_start[slot_of[cur + 16]];
        if (nxt <= cur) nxt = cur + 16;  // >16-pt voxel guard
      }
      ++g; sA[g] = nxt; cur = nxt;
    }
    sNG = g;
  }
  __syncthreads();

  // E: GEMM1 on VALU, exact f32 (K=11); row-major F -> 3x ds_read_b128
  //    broadcast per point (j is wave-uniform).
  {
    int col = t & 63;
    float w[11];
#pragma unroll
    for (int k = 0; k < 11; ++k) w[k] = W1[k * 64 + col];
    float s1 = scale1[col], sh1 = shift1[col];
    for (int j = wv; j < np; j += 4) {
      float4 f0 = *(const float4*)&uB.F[j][0];
      float4 f1 = *(const float4*)&uB.F[j][4];
      float4 f2 = *(const float4*)&uB.F[j][8];
      float acc = f0.x * w[0] + f0.y * w[1] + f0.z * w[2] + f0.w * w[3] +
                  f1.x * w[4] + f1.y * w[5] + f1.z * w[6] + f1.w * w[7] +
                  f2.x * w[8] + f2.y * w[9] + f2.z * w[10];
      Ph[j][col] = f2bf(fmaxf(acc * s1 + sh1, 0.0f));
    }
  }
  __syncthreads();

  // F: per-slot vmax of pf1 into uB.Vh (aliases dead F; bf16>=0 so u16
  //    compare == value compare)
  {
    int col = t & 63;
    for (int s = wv; s < ns; s += 4) {
      int r0 = slot_start[s], r1 = slot_start[s + 1];
      unsigned short mx = 0;
      for (int j = r0; j < r1; ++j) {
        unsigned short x = Ph[j][col];
        if (x > mx) mx = x;
      }
      uB.Vh[s][col] = mx;
    }
  }
  __syncthreads();

  // G: GEMM2 (MFMA, bf16 A x split-W2) — barrier-free group loop.
  int m = lane & 15, q = lane >> 4;
  int col = wv * 16 + m;
  BF8 b2h[4], b2l[4];
#pragma unroll
  for (int kb = 0; kb < 4; ++kb)
#pragma unroll
    for (int i = 0; i < 8; ++i)
      split_bf(W2[(kb * 32 + q * 8 + i) * 64 + col], b2h[kb].u[i],
               b2l[kb].u[i]);
  float s2 = scale2[col], sh2 = shift2[col];
  int ng = sNG;
  for (int g = 0; g < ng; ++g) {
    int base = sA[g], lim = sA[g + 1];
    int jj = base + m;
    if (jj > np - 1) jj = np - 1;  // pad rows (ignored in reduce)
    int sl = slot_of[jj];
    f32x4 c2 = {0.f, 0.f, 0.f, 0.f};
#pragma unroll
    for (int kb = 0; kb < 4; ++kb) {
      const unsigned short* ph = (kb < 2) ? &Ph[jj][kb * 32 + q * 8]
                                          : &uB.Vh[sl][(kb - 2) * 32 + q * 8];
      BF8 a;
      *(ushort4*)&a.u[0] = *(const ushort4*)ph;
      *(ushort4*)&a.u[4] = *(const ushort4*)(ph + 4);
      c2 = __builtin_amdgcn_mfma_f32_16x16x32_bf16(a.v, b2h[kb].v, c2, 0, 0, 0);
      c2 = __builtin_amdgcn_mfma_f32_16x16x32_bf16(a.v, b2l[kb].v, c2, 0, 0, 0);
    }
    // per-wave private transpose (same-wave LDS RAW is in-order: no barrier)
#pragma unroll
    for (int r = 0; r < 4; ++r)
      uA.Cst[wv][q * 4 + r][m] = fmaxf(c2[r] * s2 + sh2, 0.0f);
    int s_lo = slot_of[base], s_hi = slot_of[lim - 1];
    for (int s = s_lo + q; s <= s_hi; s += 4) {
      int r0 = slot_start[s], r1 = slot_start[s + 1];
      if (r1 > lim) r1 = lim;
      float mx = 0.f;
      for (int j = r0; j < r1; ++j)
        mx = fmaxf(mx, uA.Cst[wv][j - base][m]);
      out[(size_t)slot_vox[s] * 64 + col] = mx;
    }
  }
}

extern "C" void kernel_launch(void* const* d_in, const int* in_sizes, int n_in,
                              void* d_out, int out_size, void* d_ws, size_t ws_size,
                              hipStream_t stream) {
  const float4* feat = (const float4*)d_in[0];
  const int4* coors = (const int4*)d_in[1];
  const float* W1 = (const float*)d_in[2];
  const float* scale1 = (const float*)d_in[3];
  const float* shift1 = (const float*)d_in[4];
  const float* W2 = (const float*)d_in[5];
  const float* scale2 = (const float*)d_in[6];
  const float* shift2 = (const float*)d_in[7];
  int n = in_sizes[0] / 4;  // 500000 points

  // Workspace (~10.5 MB): cnt[kCL] | total[4] | cursor[kCL] | vid[n] | pv[n]
  unsigned int* cnt = (unsigned int*)d_ws;
  unsigned int* total = cnt + kCL;
  unsigned int* cursor = total + 4;
  unsigned int* vid = cursor + kCL;
  uint2* pv = (uint2*)(vid + ((n + 1) & ~1));

  // zero cnt + total in one memset
  hipMemsetAsync(cnt, 0, (size_t)(kCL + 4) * 4, stream);

  k_hist<<<(n + 255) / 256, 256, 0, stream>>>(coors, cnt, vid, n);
  k_alloczero<<<NBLK, 256, 0, stream>>>(cnt, total, cursor, (float4*)d_out);
  k_scatter<<<(n + 255) / 256, 256, 0, stream>>>(vid, cursor, pv, n);
  k_fused<<<(n + P - 1) / P, 256, 0, stream>>>(
      feat, pv, W1, scale1, shift1, W2, scale2, shift2, (float*)d_out, n);
}